// Round 5
// baseline (416.616 us; speedup 1.0000x reference)
//
#include <hip/hip_runtime.h>
#include <hip/hip_bf16.h>
#include <stdint.h>

typedef __bf16 bf16x8 __attribute__((ext_vector_type(8)));
typedef float f32x4 __attribute__((ext_vector_type(4)));
typedef unsigned short u16;
typedef u16 u16x8 __attribute__((ext_vector_type(8)));

__device__ __forceinline__ float bf2f(u16 u) {
  union { uint32_t i; float f; } v; v.i = uint32_t(u) << 16; return v.f;
}
__device__ __forceinline__ u16 f2bf(float f) {
  union { float f; uint32_t i; } v; v.f = f;
  uint32_t r = v.i + 0x7FFFu + ((v.i >> 16) & 1u);  // RNE
  return (u16)(r >> 16);
}
__device__ __forceinline__ uint32_t pack2(float a, float b) {
  union { __bf16 h[2]; uint32_t u; } v;
  v.h[0] = (__bf16)a; v.h[1] = (__bf16)b; return v.u;
}

// global -> LDS direct (16B per lane; LDS dest is wave-uniform base + lane*16)
typedef __attribute__((address_space(1))) const uint32_t gas_u32;
typedef __attribute__((address_space(3))) uint32_t las_u32;
__device__ __forceinline__ void gload_lds16(const u16* g, u16* l) {
  __builtin_amdgcn_global_load_lds((gas_u32*)g, (las_u32*)l, 16, 0, 0);
}

// ---------------------------------------------------------------------------
// f32 -> bf16 conversion
// ---------------------------------------------------------------------------
__global__ __launch_bounds__(256) void f32_to_bf16(
    const float* __restrict__ in, u16* __restrict__ out, int n)
{
  const int i = (blockIdx.x * 256 + threadIdx.x) * 8;
  if (i >= n) return;
  const float4 a = *reinterpret_cast<const float4*>(in + i);
  const float4 b = *reinterpret_cast<const float4*>(in + i + 4);
  u16x8 o;
  o[0] = f2bf(a.x); o[1] = f2bf(a.y); o[2] = f2bf(a.z); o[3] = f2bf(a.w);
  o[4] = f2bf(b.x); o[5] = f2bf(b.y); o[6] = f2bf(b.z); o[7] = f2bf(b.w);
  *reinterpret_cast<u16x8*>(out + i) = o;
}

// ---------------------------------------------------------------------------
// m97-structure GEMM core: C[128,128] tile, BK=32, global_load_lds staging.
// LDS linear [128][32] u16 (64B rows). Swizzle: 16B-unit col c' = c ^ ((row>>1)&3)
// applied on the GLOBAL source (write side) and on ds_read byte (read side)
// -> ds_read_b128 fragment reads have only free 2-way bank aliasing.
// ---------------------------------------------------------------------------
__device__ __forceinline__ void gemm_core_128(
    const u16* __restrict__ A, const u16* __restrict__ Bw,
    int row0, int col0, int K,
    u16* As, u16* Bs, f32x4 acc[4][4])
{
  const int tid = threadIdx.x, wv = tid >> 6, lane = tid & 63;
  const int l15 = lane & 15, lhi = lane >> 4;
  const int wr = (wv >> 1) * 64, wc = (wv & 1) * 64;

  // staging: wave wv covers 16B-units [wv*128, wv*128+128) of each tile
  const int p0 = wv * 128 + lane;
  const int row_s0 = p0 >> 2;
  const int c0 = ((p0 & 3) ^ ((row_s0 >> 1) & 3)) * 8;
  const int p1 = p0 + 64;
  const int row_s1 = p1 >> 2;
  const int c1 = ((p1 & 3) ^ ((row_s1 >> 1) & 3)) * 8;
  u16* const ldsA0 = As + (size_t)(wv * 128) * 8;
  u16* const ldsA1 = As + (size_t)(wv * 128 + 64) * 8;
  u16* const ldsB0 = Bs + (size_t)(wv * 128) * 8;
  u16* const ldsB1 = Bs + (size_t)(wv * 128 + 64) * 8;
  const u16* const gA0 = A + (size_t)(row0 + row_s0) * K + c0;
  const u16* const gA1 = A + (size_t)(row0 + row_s1) * K + c1;
  const u16* const gB0 = Bw + (size_t)(col0 + row_s0) * K + c0;
  const u16* const gB1 = Bw + (size_t)(col0 + row_s1) * K + c1;

  for (int k0 = 0; k0 < K; k0 += 32) {
    gload_lds16(gA0 + k0, ldsA0);
    gload_lds16(gA1 + k0, ldsA1);
    gload_lds16(gB0 + k0, ldsB0);
    gload_lds16(gB1 + k0, ldsB1);
    __syncthreads();

    bf16x8 af[4], bfv[4];
#pragma unroll
    for (int i = 0; i < 4; ++i) {
      const int ra = wr + i * 16 + l15;
      af[i] = *reinterpret_cast<const bf16x8*>(
          reinterpret_cast<const char*>(As) + ra * 64 + ((lhi ^ ((ra >> 1) & 3)) << 4));
      const int rb = wc + i * 16 + l15;
      bfv[i] = *reinterpret_cast<const bf16x8*>(
          reinterpret_cast<const char*>(Bs) + rb * 64 + ((lhi ^ ((rb >> 1) & 3)) << 4));
    }
#pragma unroll
    for (int mi = 0; mi < 4; ++mi)
#pragma unroll
      for (int ni = 0; ni < 4; ++ni)
        acc[mi][ni] = __builtin_amdgcn_mfma_f32_16x16x32_bf16(af[mi], bfv[ni], acc[mi][ni], 0, 0, 0);
    __syncthreads();
  }
}

template <int F32OUT, int TRANSC>
__global__ __launch_bounds__(256) void gemm_bt2(
    const u16* __restrict__ A, const u16* __restrict__ Bw, void* __restrict__ Cv,
    int N, int K, int ldc)
{
  __shared__ u16 As[128 * 32];
  __shared__ u16 Bs[128 * 32];
  const int row0 = blockIdx.y * 128, col0 = blockIdx.x * 128;
  f32x4 acc[4][4] = {};
  gemm_core_128(A, Bw, row0, col0, K, As, Bs, acc);

  const int lane = threadIdx.x & 63, wv = threadIdx.x >> 6;
  const int wr = (wv >> 1) * 64, wc = (wv & 1) * 64;
  const int l15 = lane & 15;
#pragma unroll
  for (int mi = 0; mi < 4; ++mi) {
    const int r0 = row0 + wr + mi * 16 + ((lane >> 4) << 2);
#pragma unroll
    for (int ni = 0; ni < 4; ++ni) {
      const int c = col0 + wc + ni * 16 + l15;
#pragma unroll
      for (int r = 0; r < 4; ++r) {
        if (TRANSC)
          reinterpret_cast<u16*>(Cv)[(size_t)c * ldc + (r0 + r)] = f2bf(acc[mi][ni][r]);
        else if (F32OUT)
          reinterpret_cast<float*>(Cv)[(size_t)(r0 + r) * ldc + c] = acc[mi][ni][r];
        else
          reinterpret_cast<u16*>(Cv)[(size_t)(r0 + r) * ldc + c] = f2bf(acc[mi][ni][r]);
      }
    }
  }
}

// Fused K+V projection: grid (8, 32). Blocks x<4 -> K (row-major out),
// x>=4 -> V (transposed out, feeds attention's V^T LDS staging).
__global__ __launch_bounds__(256) void gemm_kv(
    const u16* __restrict__ A, const u16* __restrict__ Wk, const u16* __restrict__ Wv,
    u16* __restrict__ Kout, u16* __restrict__ VTout, int K)
{
  __shared__ u16 As[128 * 32];
  __shared__ u16 Bs[128 * 32];
  const bool isV = blockIdx.x >= 4;
  const int col0 = (blockIdx.x & 3) * 128;
  const int row0 = blockIdx.y * 128;
  f32x4 acc[4][4] = {};
  gemm_core_128(A, isV ? Wv : Wk, row0, col0, K, As, Bs, acc);

  const int lane = threadIdx.x & 63, wv = threadIdx.x >> 6;
  const int wr = (wv >> 1) * 64, wc = (wv & 1) * 64;
  const int l15 = lane & 15;
#pragma unroll
  for (int mi = 0; mi < 4; ++mi) {
    const int r0 = row0 + wr + mi * 16 + ((lane >> 4) << 2);
#pragma unroll
    for (int ni = 0; ni < 4; ++ni) {
      const int c = col0 + wc + ni * 16 + l15;
#pragma unroll
      for (int r = 0; r < 4; ++r) {
        if (isV)
          VTout[(size_t)c * 4096 + (r0 + r)] = f2bf(acc[mi][ni][r]);
        else
          Kout[(size_t)(r0 + r) * 512 + c] = f2bf(acc[mi][ni][r]);
      }
    }
  }
}

// ---------------------------------------------------------------------------
// RoPE, in-place on Q (4096x2048) then K (4096x512).
// ---------------------------------------------------------------------------
__global__ __launch_bounds__(256) void rope_kernel(
    u16* __restrict__ Q, u16* __restrict__ Kv,
    const float* __restrict__ cosb, const float* __restrict__ sinb)
{
  const int QV = 4096 * 2048 / 8;
  const int KV = 4096 * 512 / 8;
  int t = blockIdx.x * 256 + threadIdx.x;
  u16* ptr; int shift;
  if (t < QV) { ptr = Q; shift = 11; }
  else { t -= QV; if (t >= KV) return; ptr = Kv; shift = 9; }
  const int e = t * 8;
  const int row = e >> shift;
  const int col = e & ((1 << shift) - 1);
  const int s = row & 2047;
  const int j0 = (col & 63) >> 1;
  u16* p = ptr + ((size_t)row << shift) + col;
  u16x8 x = *reinterpret_cast<const u16x8*>(p);
  u16x8 o;
#pragma unroll
  for (int q = 0; q < 4; ++q) {
    const float c  = cosb[s * 32 + j0 + q];
    const float sn = sinb[s * 32 + j0 + q];
    const float xr = bf2f(x[2 * q]), xi = bf2f(x[2 * q + 1]);
    o[2 * q]     = f2bf(xr * c - xi * sn);
    o[2 * q + 1] = f2bf(xr * sn + xi * c);
  }
  *reinterpret_cast<u16x8*>(p) = o;
}

// ---------------------------------------------------------------------------
// Swizzled-LDS helpers for attention tiles [rows][64] bf16 (128B rows),
// byte ^= ((row&7)<<4)
// ---------------------------------------------------------------------------
__device__ __forceinline__ bf16x8 lds_read8(const u16* base, int row, int col) {
  const int byte = (row * 128 + col * 2) ^ ((row & 7) << 4);
  return *reinterpret_cast<const bf16x8*>(reinterpret_cast<const char*>(base) + byte);
}
__device__ __forceinline__ void lds_write8(u16* base, int row, int col, bf16x8 v) {
  const int byte = (row * 128 + col * 2) ^ ((row & 7) << 4);
  *reinterpret_cast<bf16x8*>(reinterpret_cast<char*>(base) + byte) = v;
}
__device__ __forceinline__ void lds_write4(u16* base, int row, int col, uint32_t v) {
  const int byte = (row * 128 + col * 2) ^ ((row & 7) << 4);
  *reinterpret_cast<uint32_t*>(reinterpret_cast<char*>(base) + byte) = v;
}

__device__ __forceinline__ bf16x8 scale8(bf16x8 v) {
#pragma unroll
  for (int i = 0; i < 8; ++i) v[i] = (__bf16)((float)v[i] * 0.125f);
  return v;
}

// ---------------------------------------------------------------------------
// Softmax update for one 16-q-row set vs a 64-kv tile (swapped QK^T layout:
// lane l15 = q-row, scores spread over f (k-frag) and lhi/r).
// ---------------------------------------------------------------------------
__device__ __forceinline__ void softmax_upd(
    u16* __restrict__ Plw, const f32x4 s[4], int t0, int qbase, int l15, int lhi,
    float& mrun, float& lrun, f32x4 oacc[4], bool needmask)
{
  float v[4][4];
  float mx = -1e30f;
  if (needmask) {
#pragma unroll
    for (int f = 0; f < 4; ++f)
#pragma unroll
      for (int r = 0; r < 4; ++r) {
        float x = s[f][r];
        if (t0 + f * 16 + lhi * 4 + r > qbase + l15) x = -1e30f;
        v[f][r] = x; mx = fmaxf(mx, x);
      }
  } else {
#pragma unroll
    for (int f = 0; f < 4; ++f)
#pragma unroll
      for (int r = 0; r < 4; ++r) { v[f][r] = s[f][r]; mx = fmaxf(mx, v[f][r]); }
  }
  mx = fmaxf(mx, __shfl_xor(mx, 16));
  mx = fmaxf(mx, __shfl_xor(mx, 32));
  const float newm = fmaxf(mrun, mx);
  const float fac = __expf(mrun - newm);
  mrun = newm;
  float sum = 0.f;
#pragma unroll
  for (int f = 0; f < 4; ++f) {
    const float p0 = __expf(v[f][0] - newm), p1 = __expf(v[f][1] - newm);
    const float p2 = __expf(v[f][2] - newm), p3 = __expf(v[f][3] - newm);
    sum += (p0 + p1) + (p2 + p3);
    lds_write4(Plw, l15, f * 16 + lhi * 4,     pack2(p0, p1));
    lds_write4(Plw, l15, f * 16 + lhi * 4 + 2, pack2(p2, p3));
  }
  sum += __shfl_xor(sum, 16);
  sum += __shfl_xor(sum, 32);
  lrun = lrun * fac + sum;
  float facq[4];
#pragma unroll
  for (int r = 0; r < 4; ++r) facq[r] = __shfl(fac, lhi * 4 + r);
#pragma unroll
  for (int nf = 0; nf < 4; ++nf)
#pragma unroll
    for (int r = 0; r < 4; ++r) oacc[nf][r] *= facq[r];
}

// Dual-set tile update: shares K/V fragment reads between the two q-sets,
// independent softmaxes interleave for ILP. Separate P buffers.
__device__ __forceinline__ void attn_pair(
    const u16* __restrict__ Ks, const u16* __restrict__ Vt,
    u16* __restrict__ PlA, u16* __restrict__ PlB,
    const bf16x8 qfA[2], const bf16x8 qfB[2], int t0, int qAb, int qBb,
    int l15, int lhi,
    float& mA, float& lA, f32x4 oA[4], float& mB, float& lB, f32x4 oB[4])
{
  f32x4 sA[4] = {}, sB[4] = {};
#pragma unroll
  for (int kc = 0; kc < 2; ++kc)
#pragma unroll
    for (int f = 0; f < 4; ++f) {
      const bf16x8 kf = lds_read8(Ks, f * 16 + l15, kc * 32 + lhi * 8);
      sA[f] = __builtin_amdgcn_mfma_f32_16x16x32_bf16(kf, qfA[kc], sA[f], 0, 0, 0);
      sB[f] = __builtin_amdgcn_mfma_f32_16x16x32_bf16(kf, qfB[kc], sB[f], 0, 0, 0);
    }
  softmax_upd(PlA, sA, t0, qAb, l15, lhi, mA, lA, oA, t0 + 63 > qAb);
  softmax_upd(PlB, sB, t0, qBb, l15, lhi, mB, lB, oB, t0 + 63 > qBb);
#pragma unroll
  for (int kc = 0; kc < 2; ++kc) {
    const bf16x8 paA = lds_read8(PlA, l15, kc * 32 + lhi * 8);
    const bf16x8 paB = lds_read8(PlB, l15, kc * 32 + lhi * 8);
#pragma unroll
    for (int nf = 0; nf < 4; ++nf) {
      const bf16x8 vf = lds_read8(Vt, nf * 16 + l15, kc * 32 + lhi * 8);
      oA[nf] = __builtin_amdgcn_mfma_f32_16x16x32_bf16(paA, vf, oA[nf], 0, 0, 0);
      oB[nf] = __builtin_amdgcn_mfma_f32_16x16x32_bf16(paB, vf, oB[nf], 0, 0, 0);
    }
  }
}

__device__ __forceinline__ void attn_single(
    const u16* __restrict__ Ks, const u16* __restrict__ Vt, u16* __restrict__ Plw,
    const bf16x8 qf[2], int t0, int qbase, int l15, int lhi,
    float& mrun, float& lrun, f32x4 oacc[4])
{
  f32x4 s[4] = {};
#pragma unroll
  for (int kc = 0; kc < 2; ++kc)
#pragma unroll
    for (int f = 0; f < 4; ++f) {
      const bf16x8 kf = lds_read8(Ks, f * 16 + l15, kc * 32 + lhi * 8);
      s[f] = __builtin_amdgcn_mfma_f32_16x16x32_bf16(kf, qf[kc], s[f], 0, 0, 0);
    }
  softmax_upd(Plw, s, t0, qbase, l15, lhi, mrun, lrun, oacc, t0 + 63 > qbase);
#pragma unroll
  for (int kc = 0; kc < 2; ++kc) {
    const bf16x8 pa = lds_read8(Plw, l15, kc * 32 + lhi * 8);
#pragma unroll
    for (int nf = 0; nf < 4; ++nf) {
      const bf16x8 vf = lds_read8(Vt, nf * 16 + l15, kc * 32 + lhi * 8);
      oacc[nf] = __builtin_amdgcn_mfma_f32_16x16x32_bf16(pa, vf, oacc[nf], 0, 0, 0);
    }
  }
}

__device__ __forceinline__ void attn_store(
    u16* __restrict__ O, const size_t qoff, const int h, const int qbase,
    const int l15, const int lhi, const float lrun, const f32x4 oacc[4])
{
  float linv[4];
#pragma unroll
  for (int r = 0; r < 4; ++r) linv[r] = 1.f / __shfl(lrun, lhi * 4 + r);
#pragma unroll
  for (int nf = 0; nf < 4; ++nf)
#pragma unroll
    for (int r = 0; r < 4; ++r)
      O[qoff + (size_t)(qbase + lhi * 4 + r) * 2048 + h * 64 + nf * 16 + l15] =
          f2bf(oacc[nf][r] * linv[r]);
}

// ---------------------------------------------------------------------------
// Causal flash attention, GQA. Grid (16, 32, 2); block 256 = 4 waves.
// Balanced pairing: block j handles q-tile j AND q-tile 31-j (33 updates each).
// ---------------------------------------------------------------------------
__global__ __launch_bounds__(256, 4) void attn_kernel(
    const u16* __restrict__ Q, const u16* __restrict__ K,
    const u16* __restrict__ VT, u16* __restrict__ O)
{
  __shared__ u16 Ks[64 * 64];
  __shared__ u16 Vt[64 * 64];
  __shared__ u16 Pl[8][16 * 64];

  const int j  = blockIdx.x;            // 0..15
  const int h  = blockIdx.y;
  const int b  = blockIdx.z;
  const int kh = h >> 2;
  const int tid = threadIdx.x, wv = tid >> 6, lane = tid & 63;
  const int l15 = lane & 15, lhi = lane >> 4;
  const size_t qoff = (size_t)b * 2048 * 2048;
  const size_t koff = (size_t)b * 2048 * 512;

  const int qAb = j * 64 + wv * 16;
  const int qBb = (31 - j) * 64 + wv * 16;

  const int sr0 = tid >> 3;           // 0..31
  const int sc  = (tid & 7) * 8;

  bf16x8 qfA[2], qfB[2];
#pragma unroll
  for (int kc = 0; kc < 2; ++kc) {
    qfA[kc] = scale8(*reinterpret_cast<const bf16x8*>(
        Q + qoff + (size_t)(qAb + l15) * 2048 + h * 64 + kc * 32 + lhi * 8));
    qfB[kc] = scale8(*reinterpret_cast<const bf16x8*>(
        Q + qoff + (size_t)(qBb + l15) * 2048 + h * 64 + kc * 32 + lhi * 8));
  }

  float mA = -1e30f, lA = 0.f, mB = -1e30f, lB = 0.f;
  f32x4 oA[4] = {}, oB[4] = {};

  const int tlast = 31 - j;

  bf16x8 kv0, kv1, vt0, vt1;
  kv0 = *reinterpret_cast<const bf16x8*>(K + koff + (size_t)(sr0) * 512 + kh * 64 + sc);
  kv1 = *reinterpret_cast<const bf16x8*>(K + koff + (size_t)(sr0 + 32) * 512 + kh * 64 + sc);
  vt0 = *reinterpret_cast<const bf16x8*>(VT + (size_t)(kh * 64 + sr0) * 4096 + b * 2048 + sc);
  vt1 = *reinterpret_cast<const bf16x8*>(VT + (size_t)(kh * 64 + sr0 + 32) * 4096 + b * 2048 + sc);
  lds_write8(Ks, sr0, sc, kv0);
  lds_write8(Ks, sr0 + 32, sc, kv1);
  lds_write8(Vt, sr0, sc, vt0);
  lds_write8(Vt, sr0 + 32, sc, vt1);
  __syncthreads();

  for (int t = 0; t <= tlast; ++t) {
    const int t0 = t * 64;
    const bool more = t < tlast;
    if (more) {
      const int n0 = t0 + 64;
      kv0 = *reinterpret_cast<const bf16x8*>(K + koff + (size_t)(n0 + sr0) * 512 + kh * 64 + sc);
      kv1 = *reinterpret_cast<const bf16x8*>(K + koff + (size_t)(n0 + sr0 + 32) * 512 + kh * 64 + sc);
      vt0 = *reinterpret_cast<const bf16x8*>(VT + (size_t)(kh * 64 + sr0) * 4096 + b * 2048 + n0 + sc);
      vt1 = *reinterpret_cast<const bf16x8*>(VT + (size_t)(kh * 64 + sr0 + 32) * 4096 + b * 2048 + n0 + sc);
    }

    if (t <= j)
      attn_pair(Ks, Vt, Pl[4 + wv], Pl[wv], qfA, qfB, t0, qAb, qBb,
                l15, lhi, mA, lA, oA, mB, lB, oB);
    else
      attn_single(Ks, Vt, Pl[wv], qfB, t0, qBb, l15, lhi, mB, lB, oB);

    __syncthreads();
    if (more) {
      lds_write8(Ks, sr0, sc, kv0);
      lds_write8(Ks, sr0 + 32, sc, kv1);
      lds_write8(Vt, sr0, sc, vt0);
      lds_write8(Vt, sr0 + 32, sc, vt1);
    }
    __syncthreads();
  }

  attn_store(O, qoff, h, qAb, l15, lhi, lA, oA);
  attn_store(O, qoff, h, qBb, l15, lhi, lB, oB);
}

// ---------------------------------------------------------------------------
extern "C" void kernel_launch(void* const* d_in, const int* in_sizes, int n_in,
                              void* d_out, int out_size, void* d_ws, size_t ws_size,
                              hipStream_t stream)
{
  const float* x  = (const float*)d_in[0];
  const float* fc = (const float*)d_in[1];
  const float* fs = (const float*)d_in[2];
  // d_in[3] = mask (causal; analytic)
  const float* wq = (const float*)d_in[4];
  const float* wk = (const float*)d_in[5];
  const float* wv = (const float*)d_in[6];
  const float* wo = (const float*)d_in[7];
  float* out = (float*)d_out;

  u16* Xb  = (u16*)d_ws;                          // 4096 x 2048
  u16* Wqb = Xb  + (size_t)4096 * 2048;           // 2048 x 2048
  u16* Wkb = Wqb + (size_t)2048 * 2048;           // 512 x 2048
  u16* Wvb = Wkb + (size_t)512 * 2048;            // 512 x 2048
  u16* Qws = Wvb + (size_t)512 * 2048;            // 4096 x 2048
  u16* Kws = Qws + (size_t)4096 * 2048;           // 4096 x 512
  u16* VTws = Kws + (size_t)4096 * 512;           // 512 x 4096  (V transposed)
  u16* Ows = Xb;                                  // alias: x dead after QKV
  u16* Wob = Wqb;                                 // alias: wq dead after Q gemm

  dim3 blk(256);
  f32_to_bf16<<<dim3(4096 * 2048 / 8 / 256), blk, 0, stream>>>(x,  Xb,  4096 * 2048);
  f32_to_bf16<<<dim3(2048 * 2048 / 8 / 256), blk, 0, stream>>>(wq, Wqb, 2048 * 2048);
  f32_to_bf16<<<dim3(512 * 2048 / 8 / 256),  blk, 0, stream>>>(wk, Wkb, 512 * 2048);
  f32_to_bf16<<<dim3(512 * 2048 / 8 / 256),  blk, 0, stream>>>(wv, Wvb, 512 * 2048);
  // QKV projections
  gemm_bt2<0,0><<<dim3(16, 32), blk, 0, stream>>>(Xb, Wqb, Qws, 2048, 2048, 2048);
  gemm_kv<<<dim3(8, 32), blk, 0, stream>>>(Xb, Wkb, Wvb, Kws, VTws, 2048);
  f32_to_bf16<<<dim3(2048 * 2048 / 8 / 256), blk, 0, stream>>>(wo, Wob, 2048 * 2048);
  rope_kernel<<<dim3((4096 * 2048 / 8 + 4096 * 512 / 8) / 256), blk, 0, stream>>>(Qws, Kws, fc, fs);
  // Flash attention
  attn_kernel<<<dim3(16, 32, 2), blk, 0, stream>>>(Qws, Kws, VTws, Ows);
  // Output projection -> f32
  gemm_bt2<1,0><<<dim3(16, 32), blk, 0, stream>>>(Ows, Wob, out, 2048, 2048, 2048);
}

// Round 6
// 308.284 us; speedup vs baseline: 1.3514x; 1.3514x over previous
//
#include <hip/hip_runtime.h>
#include <hip/hip_bf16.h>
#include <stdint.h>

typedef __bf16 bf16x8 __attribute__((ext_vector_type(8)));
typedef float f32x4 __attribute__((ext_vector_type(4)));
typedef unsigned short u16;
typedef u16 u16x8 __attribute__((ext_vector_type(8)));

__device__ __forceinline__ float bf2f(u16 u) {
  union { uint32_t i; float f; } v; v.i = uint32_t(u) << 16; return v.f;
}
__device__ __forceinline__ u16 f2bf(float f) {
  union { float f; uint32_t i; } v; v.f = f;
  uint32_t r = v.i + 0x7FFFu + ((v.i >> 16) & 1u);  // RNE
  return (u16)(r >> 16);
}
__device__ __forceinline__ uint32_t pack2(float a, float b) {
  union { __bf16 h[2]; uint32_t u; } v;
  v.h[0] = (__bf16)a; v.h[1] = (__bf16)b; return v.u;
}

// global -> LDS direct (16B per lane; LDS dest is wave-uniform base + lane*16)
typedef __attribute__((address_space(1))) const uint32_t gas_u32;
typedef __attribute__((address_space(3))) uint32_t las_u32;
__device__ __forceinline__ void gload_lds16(const u16* g, u16* l) {
  __builtin_amdgcn_global_load_lds((gas_u32*)g, (las_u32*)l, 16, 0, 0);
}

// ---------------------------------------------------------------------------
// f32 -> bf16 conversion
// ---------------------------------------------------------------------------
__global__ __launch_bounds__(256) void f32_to_bf16(
    const float* __restrict__ in, u16* __restrict__ out, int n)
{
  const int i = (blockIdx.x * 256 + threadIdx.x) * 8;
  if (i >= n) return;
  const float4 a = *reinterpret_cast<const float4*>(in + i);
  const float4 b = *reinterpret_cast<const float4*>(in + i + 4);
  u16x8 o;
  o[0] = f2bf(a.x); o[1] = f2bf(a.y); o[2] = f2bf(a.z); o[3] = f2bf(a.w);
  o[4] = f2bf(b.x); o[5] = f2bf(b.y); o[6] = f2bf(b.z); o[7] = f2bf(b.w);
  *reinterpret_cast<u16x8*>(out + i) = o;
}

// ---------------------------------------------------------------------------
// m97-structure GEMM core: C[128,128] tile, BK=32, global_load_lds staging.
// LDS linear [128][32] u16 (64B rows). Swizzle: 16B-unit col c' = c ^ ((row>>1)&3)
// applied on the GLOBAL source (write side) and on ds_read byte (read side).
// ---------------------------------------------------------------------------
__device__ __forceinline__ void gemm_core_128(
    const u16* __restrict__ A, const u16* __restrict__ Bw,
    int row0, int col0, int K,
    u16* As, u16* Bs, f32x4 acc[4][4])
{
  const int tid = threadIdx.x, wv = tid >> 6, lane = tid & 63;
  const int l15 = lane & 15, lhi = lane >> 4;
  const int wr = (wv >> 1) * 64, wc = (wv & 1) * 64;

  const int p0 = wv * 128 + lane;
  const int row_s0 = p0 >> 2;
  const int c0 = ((p0 & 3) ^ ((row_s0 >> 1) & 3)) * 8;
  const int p1 = p0 + 64;
  const int row_s1 = p1 >> 2;
  const int c1 = ((p1 & 3) ^ ((row_s1 >> 1) & 3)) * 8;
  u16* const ldsA0 = As + (size_t)(wv * 128) * 8;
  u16* const ldsA1 = As + (size_t)(wv * 128 + 64) * 8;
  u16* const ldsB0 = Bs + (size_t)(wv * 128) * 8;
  u16* const ldsB1 = Bs + (size_t)(wv * 128 + 64) * 8;
  const u16* const gA0 = A + (size_t)(row0 + row_s0) * K + c0;
  const u16* const gA1 = A + (size_t)(row0 + row_s1) * K + c1;
  const u16* const gB0 = Bw + (size_t)(col0 + row_s0) * K + c0;
  const u16* const gB1 = Bw + (size_t)(col0 + row_s1) * K + c1;

  for (int k0 = 0; k0 < K; k0 += 32) {
    gload_lds16(gA0 + k0, ldsA0);
    gload_lds16(gA1 + k0, ldsA1);
    gload_lds16(gB0 + k0, ldsB0);
    gload_lds16(gB1 + k0, ldsB1);
    __syncthreads();

    bf16x8 af[4], bfv[4];
#pragma unroll
    for (int i = 0; i < 4; ++i) {
      const int ra = wr + i * 16 + l15;
      af[i] = *reinterpret_cast<const bf16x8*>(
          reinterpret_cast<const char*>(As) + ra * 64 + ((lhi ^ ((ra >> 1) & 3)) << 4));
      const int rb = wc + i * 16 + l15;
      bfv[i] = *reinterpret_cast<const bf16x8*>(
          reinterpret_cast<const char*>(Bs) + rb * 64 + ((lhi ^ ((rb >> 1) & 3)) << 4));
    }
#pragma unroll
    for (int mi = 0; mi < 4; ++mi)
#pragma unroll
      for (int ni = 0; ni < 4; ++ni)
        acc[mi][ni] = __builtin_amdgcn_mfma_f32_16x16x32_bf16(af[mi], bfv[ni], acc[mi][ni], 0, 0, 0);
    __syncthreads();
  }
}

template <int F32OUT, int TRANSC>
__global__ __launch_bounds__(256) void gemm_bt2(
    const u16* __restrict__ A, const u16* __restrict__ Bw, void* __restrict__ Cv,
    int N, int K, int ldc)
{
  __shared__ u16 As[128 * 32];
  __shared__ u16 Bs[128 * 32];
  const int row0 = blockIdx.y * 128, col0 = blockIdx.x * 128;
  f32x4 acc[4][4] = {};
  gemm_core_128(A, Bw, row0, col0, K, As, Bs, acc);

  const int lane = threadIdx.x & 63, wv = threadIdx.x >> 6;
  const int wr = (wv >> 1) * 64, wc = (wv & 1) * 64;
  const int l15 = lane & 15;
#pragma unroll
  for (int mi = 0; mi < 4; ++mi) {
    const int r0 = row0 + wr + mi * 16 + ((lane >> 4) << 2);
#pragma unroll
    for (int ni = 0; ni < 4; ++ni) {
      const int c = col0 + wc + ni * 16 + l15;
#pragma unroll
      for (int r = 0; r < 4; ++r) {
        if (TRANSC)
          reinterpret_cast<u16*>(Cv)[(size_t)c * ldc + (r0 + r)] = f2bf(acc[mi][ni][r]);
        else if (F32OUT)
          reinterpret_cast<float*>(Cv)[(size_t)(r0 + r) * ldc + c] = acc[mi][ni][r];
        else
          reinterpret_cast<u16*>(Cv)[(size_t)(r0 + r) * ldc + c] = f2bf(acc[mi][ni][r]);
      }
    }
  }
}

// Fused K+V projection: grid (8, 32). Blocks x<4 -> K, x>=4 -> V^T.
__global__ __launch_bounds__(256) void gemm_kv(
    const u16* __restrict__ A, const u16* __restrict__ Wk, const u16* __restrict__ Wv,
    u16* __restrict__ Kout, u16* __restrict__ VTout, int K)
{
  __shared__ u16 As[128 * 32];
  __shared__ u16 Bs[128 * 32];
  const bool isV = blockIdx.x >= 4;
  const int col0 = (blockIdx.x & 3) * 128;
  const int row0 = blockIdx.y * 128;
  f32x4 acc[4][4] = {};
  gemm_core_128(A, isV ? Wv : Wk, row0, col0, K, As, Bs, acc);

  const int lane = threadIdx.x & 63, wv = threadIdx.x >> 6;
  const int wr = (wv >> 1) * 64, wc = (wv & 1) * 64;
  const int l15 = lane & 15;
#pragma unroll
  for (int mi = 0; mi < 4; ++mi) {
    const int r0 = row0 + wr + mi * 16 + ((lane >> 4) << 2);
#pragma unroll
    for (int ni = 0; ni < 4; ++ni) {
      const int c = col0 + wc + ni * 16 + l15;
#pragma unroll
      for (int r = 0; r < 4; ++r) {
        if (isV)
          VTout[(size_t)c * 4096 + (r0 + r)] = f2bf(acc[mi][ni][r]);
        else
          Kout[(size_t)(r0 + r) * 512 + c] = f2bf(acc[mi][ni][r]);
      }
    }
  }
}

// ---------------------------------------------------------------------------
// RoPE, in-place on Q (4096x2048) then K (4096x512).
// ---------------------------------------------------------------------------
__global__ __launch_bounds__(256) void rope_kernel(
    u16* __restrict__ Q, u16* __restrict__ Kv,
    const float* __restrict__ cosb, const float* __restrict__ sinb)
{
  const int QV = 4096 * 2048 / 8;
  const int KV = 4096 * 512 / 8;
  int t = blockIdx.x * 256 + threadIdx.x;
  u16* ptr; int shift;
  if (t < QV) { ptr = Q; shift = 11; }
  else { t -= QV; if (t >= KV) return; ptr = Kv; shift = 9; }
  const int e = t * 8;
  const int row = e >> shift;
  const int col = e & ((1 << shift) - 1);
  const int s = row & 2047;
  const int j0 = (col & 63) >> 1;
  u16* p = ptr + ((size_t)row << shift) + col;
  u16x8 x = *reinterpret_cast<const u16x8*>(p);
  u16x8 o;
#pragma unroll
  for (int q = 0; q < 4; ++q) {
    const float c  = cosb[s * 32 + j0 + q];
    const float sn = sinb[s * 32 + j0 + q];
    const float xr = bf2f(x[2 * q]), xi = bf2f(x[2 * q + 1]);
    o[2 * q]     = f2bf(xr * c - xi * sn);
    o[2 * q + 1] = f2bf(xr * sn + xi * c);
  }
  *reinterpret_cast<u16x8*>(p) = o;
}

// ---------------------------------------------------------------------------
// Attention LDS helpers: tiles [rows][64] bf16 (128B rows), byte ^= ((row&7)<<4)
// ---------------------------------------------------------------------------
__device__ __forceinline__ bf16x8 lds_read8(const u16* base, int row, int col) {
  const int byte = (row * 128 + col * 2) ^ ((row & 7) << 4);
  return *reinterpret_cast<const bf16x8*>(reinterpret_cast<const char*>(base) + byte);
}
__device__ __forceinline__ void lds_write4(u16* base, int row, int col, uint32_t v) {
  const int byte = (row * 128 + col * 2) ^ ((row & 7) << 4);
  *reinterpret_cast<uint32_t*>(reinterpret_cast<char*>(base) + byte) = v;
}

__device__ __forceinline__ bf16x8 scale8(bf16x8 v) {
#pragma unroll
  for (int i = 0; i < 8; ++i) v[i] = (__bf16)((float)v[i] * 0.125f);
  return v;
}

// ---------------------------------------------------------------------------
// One q-set (16 rows) update vs a 64-kv tile. Swapped QK^T layout:
// lane l15 = q-row, scores spread over f (k-frag) and lhi/r.
// ---------------------------------------------------------------------------
__device__ __forceinline__ void attn_set(
    const u16* __restrict__ Ks, const u16* __restrict__ Vt, u16* __restrict__ Plw,
    const bf16x8 qf[2], int t0, int qbase, int l15, int lhi,
    float& mrun, float& lrun, f32x4 oacc[4])
{
  f32x4 s[4] = {};
#pragma unroll
  for (int kc = 0; kc < 2; ++kc)
#pragma unroll
    for (int f = 0; f < 4; ++f) {
      const bf16x8 kf = lds_read8(Ks, f * 16 + l15, kc * 32 + lhi * 8);
      s[f] = __builtin_amdgcn_mfma_f32_16x16x32_bf16(kf, qf[kc], s[f], 0, 0, 0);
    }
  const bool needmask = (t0 + 63 > qbase);
  float v[4][4];
  float mx = -1e30f;
#pragma unroll
  for (int f = 0; f < 4; ++f)
#pragma unroll
    for (int r = 0; r < 4; ++r) {
      float x = s[f][r];
      if (needmask && (t0 + f * 16 + lhi * 4 + r > qbase + l15)) x = -1e30f;
      v[f][r] = x;
      mx = fmaxf(mx, x);
    }
  mx = fmaxf(mx, __shfl_xor(mx, 16));
  mx = fmaxf(mx, __shfl_xor(mx, 32));
  const float newm = fmaxf(mrun, mx);
  const float fac = __expf(mrun - newm);
  mrun = newm;
  float sum = 0.f;
#pragma unroll
  for (int f = 0; f < 4; ++f) {
    const float p0 = __expf(v[f][0] - newm), p1 = __expf(v[f][1] - newm);
    const float p2 = __expf(v[f][2] - newm), p3 = __expf(v[f][3] - newm);
    sum += (p0 + p1) + (p2 + p3);
    lds_write4(Plw, l15, f * 16 + lhi * 4,     pack2(p0, p1));
    lds_write4(Plw, l15, f * 16 + lhi * 4 + 2, pack2(p2, p3));
  }
  sum += __shfl_xor(sum, 16);
  sum += __shfl_xor(sum, 32);
  lrun = lrun * fac + sum;
  float facq[4];
#pragma unroll
  for (int r = 0; r < 4; ++r) facq[r] = __shfl(fac, lhi * 4 + r);
#pragma unroll
  for (int nf = 0; nf < 4; ++nf)
#pragma unroll
    for (int r = 0; r < 4; ++r) oacc[nf][r] *= facq[r];
#pragma unroll
  for (int kc = 0; kc < 2; ++kc) {
    const bf16x8 pa = lds_read8(Plw, l15, kc * 32 + lhi * 8);
#pragma unroll
    for (int nf = 0; nf < 4; ++nf) {
      const bf16x8 vf = lds_read8(Vt, nf * 16 + l15, kc * 32 + lhi * 8);
      oacc[nf] = __builtin_amdgcn_mfma_f32_16x16x32_bf16(pa, vf, oacc[nf], 0, 0, 0);
    }
  }
}

__device__ __forceinline__ void attn_store(
    u16* __restrict__ O, const size_t qoff, const int h, const int qbase,
    const int l15, const int lhi, const float lrun, const f32x4 oacc[4])
{
  float linv[4];
#pragma unroll
  for (int r = 0; r < 4; ++r) linv[r] = 1.f / __shfl(lrun, lhi * 4 + r);
#pragma unroll
  for (int nf = 0; nf < 4; ++nf)
#pragma unroll
    for (int r = 0; r < 4; ++r)
      O[qoff + (size_t)(qbase + lhi * 4 + r) * 2048 + h * 64 + nf * 16 + l15] =
          f2bf(oacc[nf][r] * linv[r]);
}

// ---------------------------------------------------------------------------
// Causal flash attention, GQA. Grid (16, 32, 2); block 256 = 4 waves.
// Balanced pairing: block j handles q-tile j AND q-tile 31-j (33 updates).
// K/V^T double-buffered in LDS via global_load_lds with pre-swizzled source
// (rule #21 both-sides): 16B-unit u' = u ^ (row&7); read side uses same XOR.
// One barrier per kv-tile.
// ---------------------------------------------------------------------------
__global__ __launch_bounds__(256) void attn_kernel(
    const u16* __restrict__ Q, const u16* __restrict__ K,
    const u16* __restrict__ VT, u16* __restrict__ O)
{
  __shared__ u16 Ks[2][64 * 64];
  __shared__ u16 Vt[2][64 * 64];
  __shared__ u16 Pl[4][16 * 64];

  const int j  = blockIdx.x;            // 0..15
  const int h  = blockIdx.y;
  const int b  = blockIdx.z;
  const int kh = h >> 2;
  const int tid = threadIdx.x, wv = tid >> 6, lane = tid & 63;
  const int l15 = lane & 15, lhi = lane >> 4;
  const size_t qoff = (size_t)b * 2048 * 2048;
  const size_t koff = (size_t)b * 2048 * 512;

  const int qAb = j * 64 + wv * 16;
  const int qBb = (31 - j) * 64 + wv * 16;

  // staging geometry: idx = shot*256 + tid; row = idx>>3, 16B-unit u = idx&7,
  // pre-swizzled source unit u' = u ^ (row&7); LDS dest linear at idx*16B.
  const int idx0 = tid, idx1 = tid + 256;
  const int r0 = idx0 >> 3, u0 = (idx0 & 7) ^ (r0 & 7);
  const int r1 = idx1 >> 3, u1 = (idx1 & 7) ^ (r1 & 7);
  const u16* const kg0 = K + koff + (size_t)r0 * 512 + kh * 64 + u0 * 8;
  const u16* const kg1 = K + koff + (size_t)r1 * 512 + kh * 64 + u1 * 8;
  const u16* const vg0 = VT + (size_t)(kh * 64 + r0) * 4096 + b * 2048 + u0 * 8;
  const u16* const vg1 = VT + (size_t)(kh * 64 + r1) * 4096 + b * 2048 + u1 * 8;
  const int ld0 = wv * 512;             // u16 offset for shot 0 (wave-uniform)
  const int ld1 = 2048 + wv * 512;      // shot 1

  bf16x8 qfA[2], qfB[2];
#pragma unroll
  for (int kc = 0; kc < 2; ++kc) {
    qfA[kc] = scale8(*reinterpret_cast<const bf16x8*>(
        Q + qoff + (size_t)(qAb + l15) * 2048 + h * 64 + kc * 32 + lhi * 8));
    qfB[kc] = scale8(*reinterpret_cast<const bf16x8*>(
        Q + qoff + (size_t)(qBb + l15) * 2048 + h * 64 + kc * 32 + lhi * 8));
  }

  float mA = -1e30f, lA = 0.f, mB = -1e30f, lB = 0.f;
  f32x4 oA[4] = {}, oB[4] = {};

  const int tlast = 31 - j;

  // prologue: stage tile 0 into buf 0
  gload_lds16(kg0, &Ks[0][ld0]);
  gload_lds16(kg1, &Ks[0][ld1]);
  gload_lds16(vg0, &Vt[0][ld0]);
  gload_lds16(vg1, &Vt[0][ld1]);
  __syncthreads();

  int cur = 0;
  for (int t = 0; t <= tlast; ++t) {
    const int t0 = t * 64;
    if (t < tlast) {             // issue next tile into other buffer
      const int n0 = t0 + 64;
      const int nb = cur ^ 1;
      gload_lds16(kg0 + (size_t)n0 * 512, &Ks[nb][ld0]);
      gload_lds16(kg1 + (size_t)n0 * 512, &Ks[nb][ld1]);
      gload_lds16(vg0 + n0, &Vt[nb][ld0]);
      gload_lds16(vg1 + n0, &Vt[nb][ld1]);
    }

    if (t <= j)
      attn_set(Ks[cur], Vt[cur], Pl[wv], qfA, t0, qAb, l15, lhi, mA, lA, oA);
    attn_set(Ks[cur], Vt[cur], Pl[wv], qfB, t0, qBb, l15, lhi, mB, lB, oB);

    __syncthreads();             // drains vmcnt (loads landed) + sync readers
    cur ^= 1;
  }

  attn_store(O, qoff, h, qAb, l15, lhi, lA, oA);
  attn_store(O, qoff, h, qBb, l15, lhi, lB, oB);
}

// ---------------------------------------------------------------------------
extern "C" void kernel_launch(void* const* d_in, const int* in_sizes, int n_in,
                              void* d_out, int out_size, void* d_ws, size_t ws_size,
                              hipStream_t stream)
{
  const float* x  = (const float*)d_in[0];
  const float* fc = (const float*)d_in[1];
  const float* fs = (const float*)d_in[2];
  // d_in[3] = mask (causal; analytic)
  const float* wq = (const float*)d_in[4];
  const float* wk = (const float*)d_in[5];
  const float* wv = (const float*)d_in[6];
  const float* wo = (const float*)d_in[7];
  float* out = (float*)d_out;

  u16* Xb  = (u16*)d_ws;                          // 4096 x 2048
  u16* Wqb = Xb  + (size_t)4096 * 2048;           // 2048 x 2048
  u16* Wkb = Wqb + (size_t)2048 * 2048;           // 512 x 2048
  u16* Wvb = Wkb + (size_t)512 * 2048;            // 512 x 2048
  u16* Qws = Wvb + (size_t)512 * 2048;            // 4096 x 2048
  u16* Kws = Qws + (size_t)4096 * 2048;           // 4096 x 512
  u16* VTws = Kws + (size_t)4096 * 512;           // 512 x 4096  (V transposed)
  u16* Ows = Xb;                                  // alias: x dead after QKV
  u16* Wob = Wqb;                                 // alias: wq dead after Q gemm

  dim3 blk(256);
  f32_to_bf16<<<dim3(4096 * 2048 / 8 / 256), blk, 0, stream>>>(x,  Xb,  4096 * 2048);
  f32_to_bf16<<<dim3(2048 * 2048 / 8 / 256), blk, 0, stream>>>(wq, Wqb, 2048 * 2048);
  f32_to_bf16<<<dim3(512 * 2048 / 8 / 256),  blk, 0, stream>>>(wk, Wkb, 512 * 2048);
  f32_to_bf16<<<dim3(512 * 2048 / 8 / 256),  blk, 0, stream>>>(wv, Wvb, 512 * 2048);
  // QKV projections
  gemm_bt2<0,0><<<dim3(16, 32), blk, 0, stream>>>(Xb, Wqb, Qws, 2048, 2048, 2048);
  gemm_kv<<<dim3(8, 32), blk, 0, stream>>>(Xb, Wkb, Wvb, Kws, VTws, 2048);
  f32_to_bf16<<<dim3(2048 * 2048 / 8 / 256), blk, 0, stream>>>(wo, Wob, 2048 * 2048);
  rope_kernel<<<dim3((4096 * 2048 / 8 + 4096 * 512 / 8) / 256), blk, 0, stream>>>(Qws, Kws, fc, fs);
  // Flash attention
  attn_kernel<<<dim3(16, 32, 2), blk, 0, stream>>>(Qws, Kws, VTws, Ows);
  // Output projection -> f32
  gemm_bt2<1,0><<<dim3(16, 32), blk, 0, stream>>>(Ows, Wob, out, 2048, 2048, 2048);
}

// Round 8
// 277.230 us; speedup vs baseline: 1.5028x; 1.1120x over previous
//
#include <hip/hip_runtime.h>
#include <hip/hip_bf16.h>
#include <stdint.h>

typedef __bf16 bf16x8 __attribute__((ext_vector_type(8)));
typedef float f32x4 __attribute__((ext_vector_type(4)));
typedef unsigned short u16;
typedef u16 u16x8 __attribute__((ext_vector_type(8)));

__device__ __forceinline__ float bf2f(u16 u) {
  union { uint32_t i; float f; } v; v.i = uint32_t(u) << 16; return v.f;
}
__device__ __forceinline__ u16 f2bf(float f) {
  union { float f; uint32_t i; } v; v.f = f;
  uint32_t r = v.i + 0x7FFFu + ((v.i >> 16) & 1u);  // RNE
  return (u16)(r >> 16);
}
__device__ __forceinline__ uint32_t pack2(float a, float b) {
  union { __bf16 h[2]; uint32_t u; } v;
  v.h[0] = (__bf16)a; v.h[1] = (__bf16)b; return v.u;
}
// raw v_exp_f32: D = 2^S0
__device__ __forceinline__ float exp2x(float x) { return __builtin_amdgcn_exp2f(x); }

// global -> LDS direct (16B per lane; LDS dest is wave-uniform base + lane*16)
typedef __attribute__((address_space(1))) const uint32_t gas_u32;
typedef __attribute__((address_space(3))) uint32_t las_u32;
__device__ __forceinline__ void gload_lds16(const u16* g, u16* l) {
  __builtin_amdgcn_global_load_lds((gas_u32*)g, (las_u32*)l, 16, 0, 0);
}

// ---------------------------------------------------------------------------
// Merged f32 -> bf16 conversion for x, wq, wk, wv (one launch)
// vec8 region sizes: x 1048576 | wq 524288 | wk 131072 | wv 131072
// ---------------------------------------------------------------------------
__global__ __launch_bounds__(256) void conv4(
    const float* __restrict__ x, const float* __restrict__ wq,
    const float* __restrict__ wk, const float* __restrict__ wv,
    u16* __restrict__ Xb, u16* __restrict__ Wqb,
    u16* __restrict__ Wkb, u16* __restrict__ Wvb)
{
  int t = blockIdx.x * 256 + threadIdx.x;
  const float* src; u16* dst;
  if (t < 1048576)      { src = x;  dst = Xb; }
  else if (t < 1572864) { src = wq; dst = Wqb; t -= 1048576; }
  else if (t < 1703936) { src = wk; dst = Wkb; t -= 1572864; }
  else                  { src = wv; dst = Wvb; t -= 1703936; }
  const int i = t * 8;
  const float4 a = *reinterpret_cast<const float4*>(src + i);
  const float4 b = *reinterpret_cast<const float4*>(src + i + 4);
  u16x8 o;
  o[0] = f2bf(a.x); o[1] = f2bf(a.y); o[2] = f2bf(a.z); o[3] = f2bf(a.w);
  o[4] = f2bf(b.x); o[5] = f2bf(b.y); o[6] = f2bf(b.z); o[7] = f2bf(b.w);
  *reinterpret_cast<u16x8*>(dst + i) = o;
}

__global__ __launch_bounds__(256) void f32_to_bf16(
    const float* __restrict__ in, u16* __restrict__ out, int n)
{
  const int i = (blockIdx.x * 256 + threadIdx.x) * 8;
  if (i >= n) return;
  const float4 a = *reinterpret_cast<const float4*>(in + i);
  const float4 b = *reinterpret_cast<const float4*>(in + i + 4);
  u16x8 o;
  o[0] = f2bf(a.x); o[1] = f2bf(a.y); o[2] = f2bf(a.z); o[3] = f2bf(a.w);
  o[4] = f2bf(b.x); o[5] = f2bf(b.y); o[6] = f2bf(b.z); o[7] = f2bf(b.w);
  *reinterpret_cast<u16x8*>(out + i) = o;
}

// ---------------------------------------------------------------------------
// GEMM core, BK=64: C[128,128] tile, global_load_lds staging, 32 MFMA/barrier.
// LDS [128][64] u16 (128B rows). Swizzle (both-sides, rule #21): source 16B
// unit u' = u ^ (row&7), linear LDS dest, read byte ^= ((row&7)<<4).
// ---------------------------------------------------------------------------
__device__ __forceinline__ void gemm_core(
    const u16* __restrict__ A, const u16* __restrict__ Bw,
    int row0, int col0, int K,
    u16* As, u16* Bs, f32x4 acc[4][4])
{
  const int tid = threadIdx.x, wv = tid >> 6, lane = tid & 63;
  const int l15 = lane & 15, lhi = lane >> 4;
  const int wr = (wv >> 1) * 64, wc = (wv & 1) * 64;

  // staging: 4 shots of 256 lanes cover 128 rows x 64 cols
  int srow[4], scol[4], ldso[4];
#pragma unroll
  for (int sh = 0; sh < 4; ++sh) {
    const int idx = sh * 256 + tid;
    srow[sh] = idx >> 3;
    scol[sh] = ((idx & 7) ^ (srow[sh] & 7)) * 8;
    ldso[sh] = (sh * 256 + wv * 64) * 8;     // wave-uniform u16 offset
  }

  for (int k0 = 0; k0 < K; k0 += 64) {
#pragma unroll
    for (int sh = 0; sh < 4; ++sh)
      gload_lds16(A + (size_t)(row0 + srow[sh]) * K + k0 + scol[sh], As + ldso[sh]);
#pragma unroll
    for (int sh = 0; sh < 4; ++sh)
      gload_lds16(Bw + (size_t)(col0 + srow[sh]) * K + k0 + scol[sh], Bs + ldso[sh]);
    __syncthreads();

#pragma unroll
    for (int kc = 0; kc < 2; ++kc) {
      bf16x8 af[4], bfv[4];
#pragma unroll
      for (int i = 0; i < 4; ++i) {
        const int ra = wr + i * 16 + l15;
        af[i] = *reinterpret_cast<const bf16x8*>(
            reinterpret_cast<const char*>(As) +
            ((ra * 128 + kc * 64 + lhi * 16) ^ ((ra & 7) << 4)));
        const int rb = wc + i * 16 + l15;
        bfv[i] = *reinterpret_cast<const bf16x8*>(
            reinterpret_cast<const char*>(Bs) +
            ((rb * 128 + kc * 64 + lhi * 16) ^ ((rb & 7) << 4)));
      }
#pragma unroll
      for (int mi = 0; mi < 4; ++mi)
#pragma unroll
        for (int ni = 0; ni < 4; ++ni)
          acc[mi][ni] = __builtin_amdgcn_mfma_f32_16x16x32_bf16(af[mi], bfv[ni], acc[mi][ni], 0, 0, 0);
    }
    __syncthreads();
  }
}

template <int F32OUT, int TRANSC>
__global__ __launch_bounds__(256) void gemm_bt2(
    const u16* __restrict__ A, const u16* __restrict__ Bw, void* __restrict__ Cv,
    int N, int K, int ldc)
{
  __shared__ u16 As[128 * 64];
  __shared__ u16 Bs[128 * 64];
  const int row0 = blockIdx.y * 128, col0 = blockIdx.x * 128;
  f32x4 acc[4][4] = {};
  gemm_core(A, Bw, row0, col0, K, As, Bs, acc);

  const int lane = threadIdx.x & 63, wv = threadIdx.x >> 6;
  const int wr = (wv >> 1) * 64, wc = (wv & 1) * 64;
  const int l15 = lane & 15;
#pragma unroll
  for (int mi = 0; mi < 4; ++mi) {
    const int r0 = row0 + wr + mi * 16 + ((lane >> 4) << 2);
#pragma unroll
    for (int ni = 0; ni < 4; ++ni) {
      const int c = col0 + wc + ni * 16 + l15;
#pragma unroll
      for (int r = 0; r < 4; ++r) {
        if (TRANSC)
          reinterpret_cast<u16*>(Cv)[(size_t)c * ldc + (r0 + r)] = f2bf(acc[mi][ni][r]);
        else if (F32OUT)
          reinterpret_cast<float*>(Cv)[(size_t)(r0 + r) * ldc + c] = acc[mi][ni][r];
        else
          reinterpret_cast<u16*>(Cv)[(size_t)(r0 + r) * ldc + c] = f2bf(acc[mi][ni][r]);
      }
    }
  }
}

// Fused K+V projection: grid (8, 32). Blocks x<4 -> K, x>=4 -> V^T.
__global__ __launch_bounds__(256) void gemm_kv(
    const u16* __restrict__ A, const u16* __restrict__ Wk, const u16* __restrict__ Wv,
    u16* __restrict__ Kout, u16* __restrict__ VTout, int K)
{
  __shared__ u16 As[128 * 64];
  __shared__ u16 Bs[128 * 64];
  const bool isV = blockIdx.x >= 4;
  const int col0 = (blockIdx.x & 3) * 128;
  const int row0 = blockIdx.y * 128;
  f32x4 acc[4][4] = {};
  gemm_core(A, isV ? Wv : Wk, row0, col0, K, As, Bs, acc);

  const int lane = threadIdx.x & 63, wv = threadIdx.x >> 6;
  const int wr = (wv >> 1) * 64, wc = (wv & 1) * 64;
  const int l15 = lane & 15;
#pragma unroll
  for (int mi = 0; mi < 4; ++mi) {
    const int r0 = row0 + wr + mi * 16 + ((lane >> 4) << 2);
#pragma unroll
    for (int ni = 0; ni < 4; ++ni) {
      const int c = col0 + wc + ni * 16 + l15;
#pragma unroll
      for (int r = 0; r < 4; ++r) {
        if (isV)
          VTout[(size_t)c * 4096 + (r0 + r)] = f2bf(acc[mi][ni][r]);
        else
          Kout[(size_t)(r0 + r) * 512 + c] = f2bf(acc[mi][ni][r]);
      }
    }
  }
}

// ---------------------------------------------------------------------------
// RoPE in-place. Q additionally scaled by 0.125*log2(e) (exp2-domain softmax;
// single f32 rounding). cos/sin loaded as float4 (j0 is a multiple of 4).
// ---------------------------------------------------------------------------
__global__ __launch_bounds__(256) void rope_kernel(
    u16* __restrict__ Q, u16* __restrict__ Kv,
    const float* __restrict__ cosb, const float* __restrict__ sinb)
{
  const int QV = 4096 * 2048 / 8;
  const int KV = 4096 * 512 / 8;
  int t = blockIdx.x * 256 + threadIdx.x;
  u16* ptr; int shift; float scl;
  if (t < QV) { ptr = Q; shift = 11; scl = 0.125f * 1.44269504088896f; }
  else { t -= QV; if (t >= KV) return; ptr = Kv; shift = 9; scl = 1.f; }
  const int e = t * 8;
  const int row = e >> shift;
  const int col = e & ((1 << shift) - 1);
  const int s = row & 2047;
  const int j0 = (col & 63) >> 1;       // multiple of 4
  u16* p = ptr + ((size_t)row << shift) + col;
  u16x8 x = *reinterpret_cast<const u16x8*>(p);
  const float4 cv = *reinterpret_cast<const float4*>(cosb + s * 32 + j0);
  const float4 sv = *reinterpret_cast<const float4*>(sinb + s * 32 + j0);
  const float cf[4] = {cv.x, cv.y, cv.z, cv.w};
  const float sf[4] = {sv.x, sv.y, sv.z, sv.w};
  u16x8 o;
#pragma unroll
  for (int q = 0; q < 4; ++q) {
    const float xr = bf2f(x[2 * q]), xi = bf2f(x[2 * q + 1]);
    o[2 * q]     = f2bf((xr * cf[q] - xi * sf[q]) * scl);
    o[2 * q + 1] = f2bf((xr * sf[q] + xi * cf[q]) * scl);
  }
  *reinterpret_cast<u16x8*>(p) = o;
}

// ---------------------------------------------------------------------------
// Attention LDS helpers: tiles [rows][64] bf16 (128B rows), byte ^= ((row&7)<<4)
// ---------------------------------------------------------------------------
__device__ __forceinline__ bf16x8 lds_read8(const u16* base, int row, int col) {
  const int byte = (row * 128 + col * 2) ^ ((row & 7) << 4);
  return *reinterpret_cast<const bf16x8*>(reinterpret_cast<const char*>(base) + byte);
}
__device__ __forceinline__ void lds_write4(u16* base, int row, int col, uint32_t v) {
  const int byte = (row * 128 + col * 2) ^ ((row & 7) << 4);
  *reinterpret_cast<uint32_t*>(reinterpret_cast<char*>(base) + byte) = v;
}

// ---------------------------------------------------------------------------
// One q-set (16 rows) update vs a 64-kv tile. Swapped QK^T layout:
// lane l15 = q-row, scores spread over f (k-frag) and lhi/r.
// exp2-domain (Q pre-scaled by 0.125*log2e); T13 defer-max with THR=8.
// ---------------------------------------------------------------------------
__device__ __forceinline__ void attn_set(
    const u16* __restrict__ Ks, const u16* __restrict__ Vt, u16* __restrict__ Plw,
    const bf16x8 qf[2], int t0, int qbase, int l15, int lhi,
    float& mrun, float& lrun, f32x4 oacc[4])
{
  f32x4 s[4] = {};
#pragma unroll
  for (int kc = 0; kc < 2; ++kc)
#pragma unroll
    for (int f = 0; f < 4; ++f) {
      const bf16x8 kf = lds_read8(Ks, f * 16 + l15, kc * 32 + lhi * 8);
      s[f] = __builtin_amdgcn_mfma_f32_16x16x32_bf16(kf, qf[kc], s[f], 0, 0, 0);
    }
  const bool needmask = (t0 + 63 > qbase);
  float v[4][4];
  float mx = -1e30f;
#pragma unroll
  for (int f = 0; f < 4; ++f)
#pragma unroll
    for (int r = 0; r < 4; ++r) {
      float x = s[f][r];
      if (needmask && (t0 + f * 16 + lhi * 4 + r > qbase + l15)) x = -1e30f;
      v[f][r] = x;
      mx = fmaxf(mx, x);
    }
  mx = fmaxf(mx, __shfl_xor(mx, 16));
  mx = fmaxf(mx, __shfl_xor(mx, 32));
  // T13 defer-max: only rescale when some row's max grew past THR=8
  if (!__all(mx <= mrun + 8.f)) {
    const float newm = fmaxf(mrun, mx);
    const float fac = exp2x(mrun - newm);
    mrun = newm;
    lrun *= fac;
    float facq[4];
#pragma unroll
    for (int r = 0; r < 4; ++r) facq[r] = __shfl(fac, lhi * 4 + r);
#pragma unroll
    for (int nf = 0; nf < 4; ++nf)
#pragma unroll
      for (int r = 0; r < 4; ++r) oacc[nf][r] *= facq[r];
  }
  float sum = 0.f;
#pragma unroll
  for (int f = 0; f < 4; ++f) {
    const float p0 = exp2x(v[f][0] - mrun), p1 = exp2x(v[f][1] - mrun);
    const float p2 = exp2x(v[f][2] - mrun), p3 = exp2x(v[f][3] - mrun);
    sum += (p0 + p1) + (p2 + p3);
    lds_write4(Plw, l15, f * 16 + lhi * 4,     pack2(p0, p1));
    lds_write4(Plw, l15, f * 16 + lhi * 4 + 2, pack2(p2, p3));
  }
  sum += __shfl_xor(sum, 16);
  sum += __shfl_xor(sum, 32);
  lrun += sum;
#pragma unroll
  for (int kc = 0; kc < 2; ++kc) {
    const bf16x8 pa = lds_read8(Plw, l15, kc * 32 + lhi * 8);
#pragma unroll
    for (int nf = 0; nf < 4; ++nf) {
      const bf16x8 vf = lds_read8(Vt, nf * 16 + l15, kc * 32 + lhi * 8);
      oacc[nf] = __builtin_amdgcn_mfma_f32_16x16x32_bf16(pa, vf, oacc[nf], 0, 0, 0);
    }
  }
}

__device__ __forceinline__ void attn_store(
    u16* __restrict__ O, const size_t qoff, const int h, const int qbase,
    const int l15, const int lhi, const float lrun, const f32x4 oacc[4])
{
  float linv[4];
#pragma unroll
  for (int r = 0; r < 4; ++r) linv[r] = 1.f / __shfl(lrun, lhi * 4 + r);
#pragma unroll
  for (int nf = 0; nf < 4; ++nf)
#pragma unroll
    for (int r = 0; r < 4; ++r)
      O[qoff + (size_t)(qbase + lhi * 4 + r) * 2048 + h * 64 + nf * 16 + l15] =
          f2bf(oacc[nf][r] * linv[r]);
}

// ---------------------------------------------------------------------------
// Causal flash attention, GQA. Grid (16, 32, 2); block 256 = 4 waves.
// Balanced pairing: block j handles q-tile j AND q-tile 31-j (33 updates).
// K/V^T double-buffered via global_load_lds with pre-swizzled source.
// ---------------------------------------------------------------------------
__global__ __launch_bounds__(256) void attn_kernel(
    const u16* __restrict__ Q, const u16* __restrict__ K,
    const u16* __restrict__ VT, u16* __restrict__ O)
{
  __shared__ u16 Ks[2][64 * 64];
  __shared__ u16 Vt[2][64 * 64];
  __shared__ u16 Pl[4][16 * 64];

  const int j  = blockIdx.x;            // 0..15
  const int h  = blockIdx.y;
  const int b  = blockIdx.z;
  const int kh = h >> 2;
  const int tid = threadIdx.x, wv = tid >> 6, lane = tid & 63;
  const int l15 = lane & 15, lhi = lane >> 4;
  const size_t qoff = (size_t)b * 2048 * 2048;
  const size_t koff = (size_t)b * 2048 * 512;

  const int qAb = j * 64 + wv * 16;
  const int qBb = (31 - j) * 64 + wv * 16;

  const int idx0 = tid, idx1 = tid + 256;
  const int r0 = idx0 >> 3, u0 = (idx0 & 7) ^ (r0 & 7);
  const int r1 = idx1 >> 3, u1 = (idx1 & 7) ^ (r1 & 7);
  const u16* const kg0 = K + koff + (size_t)r0 * 512 + kh * 64 + u0 * 8;
  const u16* const kg1 = K + koff + (size_t)r1 * 512 + kh * 64 + u1 * 8;
  const u16* const vg0 = VT + (size_t)(kh * 64 + r0) * 4096 + b * 2048 + u0 * 8;
  const u16* const vg1 = VT + (size_t)(kh * 64 + r1) * 4096 + b * 2048 + u1 * 8;
  const int ld0 = wv * 512;
  const int ld1 = 2048 + wv * 512;

  bf16x8 qfA[2], qfB[2];
#pragma unroll
  for (int kc = 0; kc < 2; ++kc) {
    qfA[kc] = *reinterpret_cast<const bf16x8*>(
        Q + qoff + (size_t)(qAb + l15) * 2048 + h * 64 + kc * 32 + lhi * 8);
    qfB[kc] = *reinterpret_cast<const bf16x8*>(
        Q + qoff + (size_t)(qBb + l15) * 2048 + h * 64 + kc * 32 + lhi * 8);
  }

  float mA = -1e30f, lA = 0.f, mB = -1e30f, lB = 0.f;
  f32x4 oA[4] = {}, oB[4] = {};

  const int tlast = 31 - j;

  gload_lds16(kg0, &Ks[0][ld0]);
  gload_lds16(kg1, &Ks[0][ld1]);
  gload_lds16(vg0, &Vt[0][ld0]);
  gload_lds16(vg1, &Vt[0][ld1]);
  __syncthreads();

  int cur = 0;
  for (int t = 0; t <= tlast; ++t) {
    const int t0 = t * 64;
    if (t < tlast) {
      const int n0 = t0 + 64;
      const int nb = cur ^ 1;
      gload_lds16(kg0 + (size_t)n0 * 512, &Ks[nb][ld0]);
      gload_lds16(kg1 + (size_t)n0 * 512, &Ks[nb][ld1]);
      gload_lds16(vg0 + n0, &Vt[nb][ld0]);
      gload_lds16(vg1 + n0, &Vt[nb][ld1]);
    }

    if (t <= j)
      attn_set(Ks[cur], Vt[cur], Pl[wv], qfA, t0, qAb, l15, lhi, mA, lA, oA);
    attn_set(Ks[cur], Vt[cur], Pl[wv], qfB, t0, qBb, l15, lhi, mB, lB, oB);

    __syncthreads();
    cur ^= 1;
  }

  attn_store(O, qoff, h, qAb, l15, lhi, lA, oA);
  attn_store(O, qoff, h, qBb, l15, lhi, lB, oB);
}

// ---------------------------------------------------------------------------
extern "C" void kernel_launch(void* const* d_in, const int* in_sizes, int n_in,
                              void* d_out, int out_size, void* d_ws, size_t ws_size,
                              hipStream_t stream)
{
  const float* x  = (const float*)d_in[0];
  const float* fc = (const float*)d_in[1];
  const float* fs = (const float*)d_in[2];
  // d_in[3] = mask (causal; analytic)
  const float* wq = (const float*)d_in[4];
  const float* wk = (const float*)d_in[5];
  const float* wv = (const float*)d_in[6];
  const float* wo = (const float*)d_in[7];
  float* out = (float*)d_out;

  u16* Xb  = (u16*)d_ws;                          // 4096 x 2048
  u16* Wqb = Xb  + (size_t)4096 * 2048;           // 2048 x 2048
  u16* Wkb = Wqb + (size_t)2048 * 2048;           // 512 x 2048
  u16* Wvb = Wkb + (size_t)512 * 2048;            // 512 x 2048
  u16* Qws = Wvb + (size_t)512 * 2048;            // 4096 x 2048
  u16* Kws = Qws + (size_t)4096 * 2048;           // 4096 x 512
  u16* VTws = Kws + (size_t)4096 * 512;           // 512 x 4096  (V transposed)
  u16* Ows = Xb;                                  // alias: x dead after QKV
  u16* Wob = Wqb;                                 // alias: wq dead after Q gemm

  dim3 blk(256);
  conv4<<<dim3((1048576 + 524288 + 131072 + 131072) / 256), blk, 0, stream>>>(
      x, wq, wk, wv, Xb, Wqb, Wkb, Wvb);
  // QKV projections
  gemm_bt2<0,0><<<dim3(16, 32), blk, 0, stream>>>(Xb, Wqb, Qws, 2048, 2048, 2048);
  gemm_kv<<<dim3(8, 32), blk, 0, stream>>>(Xb, Wkb, Wvb, Kws, VTws, 2048);
  f32_to_bf16<<<dim3(2048 * 2048 / 8 / 256), blk, 0, stream>>>(wo, Wob, 2048 * 2048);
  rope_kernel<<<dim3((4096 * 2048 / 8 + 4096 * 512 / 8) / 256), blk, 0, stream>>>(Qws, Kws, fc, fs);
  // Flash attention
  attn_kernel<<<dim3(16, 32, 2), blk, 0, stream>>>(Qws, Kws, VTws, Ows);
  // Output projection -> f32
  gemm_bt2<1,0><<<dim3(16, 32), blk, 0, stream>>>(Ows, Wob, out, 2048, 2048, 2048);
}

// Round 9
// 272.414 us; speedup vs baseline: 1.5293x; 1.0177x over previous
//
#include <hip/hip_runtime.h>
#include <hip/hip_bf16.h>
#include <stdint.h>

typedef __bf16 bf16x8 __attribute__((ext_vector_type(8)));
typedef float f32x4 __attribute__((ext_vector_type(4)));
typedef unsigned short u16;
typedef u16 u16x8 __attribute__((ext_vector_type(8)));

__device__ __forceinline__ float bf2f(u16 u) {
  union { uint32_t i; float f; } v; v.i = uint32_t(u) << 16; return v.f;
}
__device__ __forceinline__ u16 f2bf(float f) {
  union { float f; uint32_t i; } v; v.f = f;
  uint32_t r = v.i + 0x7FFFu + ((v.i >> 16) & 1u);  // RNE
  return (u16)(r >> 16);
}
__device__ __forceinline__ uint32_t pack2(float a, float b) {
  union { __bf16 h[2]; uint32_t u; } v;
  v.h[0] = (__bf16)a; v.h[1] = (__bf16)b; return v.u;
}
// raw v_exp_f32: D = 2^S0
__device__ __forceinline__ float exp2x(float x) { return __builtin_amdgcn_exp2f(x); }
// clang fuses nested fmaxf to v_max3_f32 (T17)
__device__ __forceinline__ float max3f(float a, float b, float c) {
  return fmaxf(fmaxf(a, b), c);
}

// global -> LDS direct (16B per lane; LDS dest is wave-uniform base + lane*16)
typedef __attribute__((address_space(1))) const uint32_t gas_u32;
typedef __attribute__((address_space(3))) uint32_t las_u32;
__device__ __forceinline__ void gload_lds16(const u16* g, u16* l) {
  __builtin_amdgcn_global_load_lds((gas_u32*)g, (las_u32*)l, 16, 0, 0);
}

// ---------------------------------------------------------------------------
// Merged f32 -> bf16 conversion for x, wq, wk, wv (one launch)
// ---------------------------------------------------------------------------
__global__ __launch_bounds__(256) void conv4(
    const float* __restrict__ x, const float* __restrict__ wq,
    const float* __restrict__ wk, const float* __restrict__ wv,
    u16* __restrict__ Xb, u16* __restrict__ Wqb,
    u16* __restrict__ Wkb, u16* __restrict__ Wvb)
{
  int t = blockIdx.x * 256 + threadIdx.x;
  const float* src; u16* dst;
  if (t < 1048576)      { src = x;  dst = Xb; }
  else if (t < 1572864) { src = wq; dst = Wqb; t -= 1048576; }
  else if (t < 1703936) { src = wk; dst = Wkb; t -= 1572864; }
  else                  { src = wv; dst = Wvb; t -= 1703936; }
  const int i = t * 8;
  const float4 a = *reinterpret_cast<const float4*>(src + i);
  const float4 b = *reinterpret_cast<const float4*>(src + i + 4);
  u16x8 o;
  o[0] = f2bf(a.x); o[1] = f2bf(a.y); o[2] = f2bf(a.z); o[3] = f2bf(a.w);
  o[4] = f2bf(b.x); o[5] = f2bf(b.y); o[6] = f2bf(b.z); o[7] = f2bf(b.w);
  *reinterpret_cast<u16x8*>(dst + i) = o;
}

__global__ __launch_bounds__(256) void f32_to_bf16(
    const float* __restrict__ in, u16* __restrict__ out, int n)
{
  const int i = (blockIdx.x * 256 + threadIdx.x) * 8;
  if (i >= n) return;
  const float4 a = *reinterpret_cast<const float4*>(in + i);
  const float4 b = *reinterpret_cast<const float4*>(in + i + 4);
  u16x8 o;
  o[0] = f2bf(a.x); o[1] = f2bf(a.y); o[2] = f2bf(a.z); o[3] = f2bf(a.w);
  o[4] = f2bf(b.x); o[5] = f2bf(b.y); o[6] = f2bf(b.z); o[7] = f2bf(b.w);
  *reinterpret_cast<u16x8*>(out + i) = o;
}

// ---------------------------------------------------------------------------
// GEMM core, BK=64: C[128,128] tile, global_load_lds staging, 32 MFMA/barrier.
// LDS [128][64] u16 (128B rows). Swizzle (both-sides): source 16B unit
// u' = u ^ (row&7), linear LDS dest, read byte ^= ((row&7)<<4).
// ---------------------------------------------------------------------------
__device__ __forceinline__ void gemm_core(
    const u16* __restrict__ A, const u16* __restrict__ Bw,
    int row0, int col0, int K,
    u16* As, u16* Bs, f32x4 acc[4][4])
{
  const int tid = threadIdx.x, wv = tid >> 6, lane = tid & 63;
  const int l15 = lane & 15, lhi = lane >> 4;
  const int wr = (wv >> 1) * 64, wc = (wv & 1) * 64;

  int srow[4], scol[4], ldso[4];
#pragma unroll
  for (int sh = 0; sh < 4; ++sh) {
    const int idx = sh * 256 + tid;
    srow[sh] = idx >> 3;
    scol[sh] = ((idx & 7) ^ (srow[sh] & 7)) * 8;
    ldso[sh] = (sh * 256 + wv * 64) * 8;
  }

  for (int k0 = 0; k0 < K; k0 += 64) {
#pragma unroll
    for (int sh = 0; sh < 4; ++sh)
      gload_lds16(A + (size_t)(row0 + srow[sh]) * K + k0 + scol[sh], As + ldso[sh]);
#pragma unroll
    for (int sh = 0; sh < 4; ++sh)
      gload_lds16(Bw + (size_t)(col0 + srow[sh]) * K + k0 + scol[sh], Bs + ldso[sh]);
    __syncthreads();

#pragma unroll
    for (int kc = 0; kc < 2; ++kc) {
      bf16x8 af[4], bfv[4];
#pragma unroll
      for (int i = 0; i < 4; ++i) {
        const int ra = wr + i * 16 + l15;
        af[i] = *reinterpret_cast<const bf16x8*>(
            reinterpret_cast<const char*>(As) +
            ((ra * 128 + kc * 64 + lhi * 16) ^ ((ra & 7) << 4)));
        const int rb = wc + i * 16 + l15;
        bfv[i] = *reinterpret_cast<const bf16x8*>(
            reinterpret_cast<const char*>(Bs) +
            ((rb * 128 + kc * 64 + lhi * 16) ^ ((rb & 7) << 4)));
      }
#pragma unroll
      for (int mi = 0; mi < 4; ++mi)
#pragma unroll
        for (int ni = 0; ni < 4; ++ni)
          acc[mi][ni] = __builtin_amdgcn_mfma_f32_16x16x32_bf16(af[mi], bfv[ni], acc[mi][ni], 0, 0, 0);
    }
    __syncthreads();
  }
}

template <int F32OUT, int TRANSC>
__global__ __launch_bounds__(256) void gemm_bt2(
    const u16* __restrict__ A, const u16* __restrict__ Bw, void* __restrict__ Cv,
    int N, int K, int ldc)
{
  __shared__ u16 As[128 * 64];
  __shared__ u16 Bs[128 * 64];
  // T1 XCD-aware swizzle (nwg % 8 == 0 for all our grids)
  const int nwg = gridDim.x * gridDim.y;
  int lin = blockIdx.y * gridDim.x + blockIdx.x;
  lin = (lin & 7) * (nwg >> 3) + (lin >> 3);
  const int row0 = (lin / gridDim.x) * 128, col0 = (lin % gridDim.x) * 128;
  f32x4 acc[4][4] = {};
  gemm_core(A, Bw, row0, col0, K, As, Bs, acc);

  const int lane = threadIdx.x & 63, wv = threadIdx.x >> 6;
  const int wr = (wv >> 1) * 64, wc = (wv & 1) * 64;
  const int l15 = lane & 15;
#pragma unroll
  for (int mi = 0; mi < 4; ++mi) {
    const int r0 = row0 + wr + mi * 16 + ((lane >> 4) << 2);
#pragma unroll
    for (int ni = 0; ni < 4; ++ni) {
      const int c = col0 + wc + ni * 16 + l15;
#pragma unroll
      for (int r = 0; r < 4; ++r) {
        if (TRANSC)
          reinterpret_cast<u16*>(Cv)[(size_t)c * ldc + (r0 + r)] = f2bf(acc[mi][ni][r]);
        else if (F32OUT)
          reinterpret_cast<float*>(Cv)[(size_t)(r0 + r) * ldc + c] = acc[mi][ni][r];
        else
          reinterpret_cast<u16*>(Cv)[(size_t)(r0 + r) * ldc + c] = f2bf(acc[mi][ni][r]);
      }
    }
  }
}

// Fused K+V projection: 256 blocks. bx<4 -> K, bx>=4 -> V^T.
__global__ __launch_bounds__(256) void gemm_kv(
    const u16* __restrict__ A, const u16* __restrict__ Wk, const u16* __restrict__ Wv,
    u16* __restrict__ Kout, u16* __restrict__ VTout, int K)
{
  __shared__ u16 As[128 * 64];
  __shared__ u16 Bs[128 * 64];
  int lin = blockIdx.y * 8 + blockIdx.x;
  lin = (lin & 7) * 32 + (lin >> 3);          // nwg=256
  const int bx = lin & 7, by = lin >> 3;
  const bool isV = bx >= 4;
  const int col0 = (bx & 3) * 128;
  const int row0 = by * 128;
  f32x4 acc[4][4] = {};
  gemm_core(A, isV ? Wv : Wk, row0, col0, K, As, Bs, acc);

  const int lane = threadIdx.x & 63, wv = threadIdx.x >> 6;
  const int wr = (wv >> 1) * 64, wc = (wv & 1) * 64;
  const int l15 = lane & 15;
#pragma unroll
  for (int mi = 0; mi < 4; ++mi) {
    const int r0 = row0 + wr + mi * 16 + ((lane >> 4) << 2);
#pragma unroll
    for (int ni = 0; ni < 4; ++ni) {
      const int c = col0 + wc + ni * 16 + l15;
#pragma unroll
      for (int r = 0; r < 4; ++r) {
        if (isV)
          VTout[(size_t)c * 4096 + (r0 + r)] = f2bf(acc[mi][ni][r]);
        else
          Kout[(size_t)(r0 + r) * 512 + c] = f2bf(acc[mi][ni][r]);
      }
    }
  }
}

// ---------------------------------------------------------------------------
// RoPE in-place. Q additionally scaled by 0.125*log2(e) (exp2-domain softmax).
// ---------------------------------------------------------------------------
__global__ __launch_bounds__(256) void rope_kernel(
    u16* __restrict__ Q, u16* __restrict__ Kv,
    const float* __restrict__ cosb, const float* __restrict__ sinb)
{
  const int QV = 4096 * 2048 / 8;
  const int KV = 4096 * 512 / 8;
  int t = blockIdx.x * 256 + threadIdx.x;
  u16* ptr; int shift; float scl;
  if (t < QV) { ptr = Q; shift = 11; scl = 0.125f * 1.44269504088896f; }
  else { t -= QV; if (t >= KV) return; ptr = Kv; shift = 9; scl = 1.f; }
  const int e = t * 8;
  const int row = e >> shift;
  const int col = e & ((1 << shift) - 1);
  const int s = row & 2047;
  const int j0 = (col & 63) >> 1;
  u16* p = ptr + ((size_t)row << shift) + col;
  u16x8 x = *reinterpret_cast<const u16x8*>(p);
  const float4 cv = *reinterpret_cast<const float4*>(cosb + s * 32 + j0);
  const float4 sv = *reinterpret_cast<const float4*>(sinb + s * 32 + j0);
  const float cf[4] = {cv.x, cv.y, cv.z, cv.w};
  const float sf[4] = {sv.x, sv.y, sv.z, sv.w};
  u16x8 o;
#pragma unroll
  for (int q = 0; q < 4; ++q) {
    const float xr = bf2f(x[2 * q]), xi = bf2f(x[2 * q + 1]);
    o[2 * q]     = f2bf((xr * cf[q] - xi * sf[q]) * scl);
    o[2 * q + 1] = f2bf((xr * sf[q] + xi * cf[q]) * scl);
  }
  *reinterpret_cast<u16x8*>(p) = o;
}

// ---------------------------------------------------------------------------
// Attention LDS helpers: tiles [rows][64] bf16 (128B rows), byte ^= ((row&7)<<4)
// ---------------------------------------------------------------------------
__device__ __forceinline__ bf16x8 lds_read8(const u16* base, int row, int col) {
  const int byte = (row * 128 + col * 2) ^ ((row & 7) << 4);
  return *reinterpret_cast<const bf16x8*>(reinterpret_cast<const char*>(base) + byte);
}
__device__ __forceinline__ void lds_write4(u16* base, int row, int col, uint32_t v) {
  const int byte = (row * 128 + col * 2) ^ ((row & 7) << 4);
  *reinterpret_cast<uint32_t*>(reinterpret_cast<char*>(base) + byte) = v;
}

// ---------------------------------------------------------------------------
// One q-set (16 rows) update vs a 64-kv tile. Swapped QK^T layout
// (lane l15 = q-row). exp2-domain; T13 defer-max (THR=8).
// Row-sum via ones-operand MFMA: lrun is f32x4 in C-layout (q = 4*lhi + r),
// which is exactly attn_store's layout -> no shfl anywhere in the sum path.
// ---------------------------------------------------------------------------
__device__ __forceinline__ void attn_set(
    const u16* __restrict__ Ks, const u16* __restrict__ Vt, u16* __restrict__ Plw,
    const bf16x8 qf[2], const bf16x8 ones, int t0, int qbase, int l15, int lhi,
    float& mrun, f32x4& lrun, f32x4 oacc[4])
{
  f32x4 s[4] = {};
#pragma unroll
  for (int kc = 0; kc < 2; ++kc)
#pragma unroll
    for (int f = 0; f < 4; ++f) {
      const bf16x8 kf = lds_read8(Ks, f * 16 + l15, kc * 32 + lhi * 8);
      s[f] = __builtin_amdgcn_mfma_f32_16x16x32_bf16(kf, qf[kc], s[f], 0, 0, 0);
    }
  const bool needmask = (t0 + 63 > qbase);
  float v[4][4];
#pragma unroll
  for (int f = 0; f < 4; ++f)
#pragma unroll
    for (int r = 0; r < 4; ++r) {
      float x = s[f][r];
      if (needmask && (t0 + f * 16 + lhi * 4 + r > qbase + l15)) x = -1e30f;
      v[f][r] = x;
    }
  // max via v_max3 tree (8 ops)
  float t1 = max3f(v[0][0], v[0][1], v[0][2]);
  float t2 = max3f(v[0][3], v[1][0], v[1][1]);
  float t3 = max3f(v[1][2], v[1][3], v[2][0]);
  float t4 = max3f(v[2][1], v[2][2], v[2][3]);
  float t5 = max3f(v[3][0], v[3][1], v[3][2]);
  float mx = fmaxf(max3f(t1, t2, t3), max3f(t4, t5, v[3][3]));
  mx = fmaxf(mx, __shfl_xor(mx, 16));
  mx = fmaxf(mx, __shfl_xor(mx, 32));
  // T13 defer-max: only rescale when some row's max grew past THR=8
  if (!__all(mx <= mrun + 8.f)) {
    const float newm = fmaxf(mrun, mx);
    const float fac = exp2x(mrun - newm);
    mrun = newm;
    float facq[4];
#pragma unroll
    for (int r = 0; r < 4; ++r) facq[r] = __shfl(fac, lhi * 4 + r);
#pragma unroll
    for (int r = 0; r < 4; ++r) lrun[r] *= facq[r];
#pragma unroll
    for (int nf = 0; nf < 4; ++nf)
#pragma unroll
      for (int r = 0; r < 4; ++r) oacc[nf][r] *= facq[r];
  }
#pragma unroll
  for (int f = 0; f < 4; ++f) {
    const float p0 = exp2x(v[f][0] - mrun), p1 = exp2x(v[f][1] - mrun);
    const float p2 = exp2x(v[f][2] - mrun), p3 = exp2x(v[f][3] - mrun);
    lds_write4(Plw, l15, f * 16 + lhi * 4,     pack2(p0, p1));
    lds_write4(Plw, l15, f * 16 + lhi * 4 + 2, pack2(p2, p3));
  }
#pragma unroll
  for (int kc = 0; kc < 2; ++kc) {
    const bf16x8 pa = lds_read8(Plw, l15, kc * 32 + lhi * 8);
    lrun = __builtin_amdgcn_mfma_f32_16x16x32_bf16(pa, ones, lrun, 0, 0, 0);
#pragma unroll
    for (int nf = 0; nf < 4; ++nf) {
      const bf16x8 vf = lds_read8(Vt, nf * 16 + l15, kc * 32 + lhi * 8);
      oacc[nf] = __builtin_amdgcn_mfma_f32_16x16x32_bf16(pa, vf, oacc[nf], 0, 0, 0);
    }
  }
}

__device__ __forceinline__ void attn_store(
    u16* __restrict__ O, const size_t qoff, const int h, const int qbase,
    const int l15, const int lhi, const f32x4 lrun, const f32x4 oacc[4])
{
  float linv[4];
#pragma unroll
  for (int r = 0; r < 4; ++r) linv[r] = 1.f / lrun[r];
#pragma unroll
  for (int nf = 0; nf < 4; ++nf)
#pragma unroll
    for (int r = 0; r < 4; ++r)
      O[qoff + (size_t)(qbase + lhi * 4 + r) * 2048 + h * 64 + nf * 16 + l15] =
          f2bf(oacc[nf][r] * linv[r]);
}

// ---------------------------------------------------------------------------
// Causal flash attention, GQA. Grid (16, 32, 2); block 256 = 4 waves.
// Balanced pairing: block j handles q-tile j AND q-tile 31-j (33 updates).
// K/V^T double-buffered via global_load_lds with pre-swizzled source.
// ---------------------------------------------------------------------------
__global__ __launch_bounds__(256) void attn_kernel(
    const u16* __restrict__ Q, const u16* __restrict__ K,
    const u16* __restrict__ VT, u16* __restrict__ O)
{
  __shared__ u16 Ks[2][64 * 64];
  __shared__ u16 Vt[2][64 * 64];
  __shared__ u16 Pl[4][16 * 64];

  const int j  = blockIdx.x;            // 0..15
  const int h  = blockIdx.y;
  const int b  = blockIdx.z;
  const int kh = h >> 2;
  const int tid = threadIdx.x, wv = tid >> 6, lane = tid & 63;
  const int l15 = lane & 15, lhi = lane >> 4;
  const size_t qoff = (size_t)b * 2048 * 2048;
  const size_t koff = (size_t)b * 2048 * 512;

  const int qAb = j * 64 + wv * 16;
  const int qBb = (31 - j) * 64 + wv * 16;

  const int idx0 = tid, idx1 = tid + 256;
  const int r0 = idx0 >> 3, u0 = (idx0 & 7) ^ (r0 & 7);
  const int r1 = idx1 >> 3, u1 = (idx1 & 7) ^ (r1 & 7);
  const u16* const kg0 = K + koff + (size_t)r0 * 512 + kh * 64 + u0 * 8;
  const u16* const kg1 = K + koff + (size_t)r1 * 512 + kh * 64 + u1 * 8;
  const u16* const vg0 = VT + (size_t)(kh * 64 + r0) * 4096 + b * 2048 + u0 * 8;
  const u16* const vg1 = VT + (size_t)(kh * 64 + r1) * 4096 + b * 2048 + u1 * 8;
  const int ld0 = wv * 512;
  const int ld1 = 2048 + wv * 512;

  bf16x8 qfA[2], qfB[2];
#pragma unroll
  for (int kc = 0; kc < 2; ++kc) {
    qfA[kc] = *reinterpret_cast<const bf16x8*>(
        Q + qoff + (size_t)(qAb + l15) * 2048 + h * 64 + kc * 32 + lhi * 8);
    qfB[kc] = *reinterpret_cast<const bf16x8*>(
        Q + qoff + (size_t)(qBb + l15) * 2048 + h * 64 + kc * 32 + lhi * 8);
  }
  bf16x8 ones;
#pragma unroll
  for (int i = 0; i < 8; ++i) ones[i] = (__bf16)1.0f;

  float mA = -1e30f, mB = -1e30f;
  f32x4 lA = {}, lB = {};
  f32x4 oA[4] = {}, oB[4] = {};

  const int tlast = 31 - j;

  gload_lds16(kg0, &Ks[0][ld0]);
  gload_lds16(kg1, &Ks[0][ld1]);
  gload_lds16(vg0, &Vt[0][ld0]);
  gload_lds16(vg1, &Vt[0][ld1]);
  __syncthreads();

  int cur = 0;
  for (int t = 0; t <= tlast; ++t) {
    const int t0 = t * 64;
    if (t < tlast) {
      const int n0 = t0 + 64;
      const int nb = cur ^ 1;
      gload_lds16(kg0 + (size_t)n0 * 512, &Ks[nb][ld0]);
      gload_lds16(kg1 + (size_t)n0 * 512, &Ks[nb][ld1]);
      gload_lds16(vg0 + n0, &Vt[nb][ld0]);
      gload_lds16(vg1 + n0, &Vt[nb][ld1]);
    }

    if (t <= j)
      attn_set(Ks[cur], Vt[cur], Pl[wv], qfA, ones, t0, qAb, l15, lhi, mA, lA, oA);
    attn_set(Ks[cur], Vt[cur], Pl[wv], qfB, ones, t0, qBb, l15, lhi, mB, lB, oB);

    __syncthreads();
    cur ^= 1;
  }

  attn_store(O, qoff, h, qAb, l15, lhi, lA, oA);
  attn_store(O, qoff, h, qBb, l15, lhi, lB, oB);
}

// ---------------------------------------------------------------------------
extern "C" void kernel_launch(void* const* d_in, const int* in_sizes, int n_in,
                              void* d_out, int out_size, void* d_ws, size_t ws_size,
                              hipStream_t stream)
{
  const float* x  = (const float*)d_in[0];
  const float* fc = (const float*)d_in[1];
  const float* fs = (const float*)d_in[2];
  // d_in[3] = mask (causal; analytic)
  const float* wq = (const float*)d_in[4];
  const float* wk = (const float*)d_in[5];
  const float* wv = (const float*)d_in[6];
  const float* wo = (const float*)d_in[7];
  float* out = (float*)d_out;

  u16* Xb  = (u16*)d_ws;                          // 4096 x 2048
  u16* Wqb = Xb  + (size_t)4096 * 2048;           // 2048 x 2048
  u16* Wkb = Wqb + (size_t)2048 * 2048;           // 512 x 2048
  u16* Wvb = Wkb + (size_t)512 * 2048;            // 512 x 2048
  u16* Qws = Wvb + (size_t)512 * 2048;            // 4096 x 2048
  u16* Kws = Qws + (size_t)4096 * 2048;           // 4096 x 512
  u16* VTws = Kws + (size_t)4096 * 512;           // 512 x 4096  (V transposed)
  u16* Ows = Xb;                                  // alias: x dead after QKV
  u16* Wob = Wqb;                                 // alias: wq dead after Q gemm

  dim3 blk(256);
  conv4<<<dim3((1048576 + 524288 + 131072 + 131072) / 256), blk, 0, stream>>>(
      x, wq, wk, wv, Xb, Wqb, Wkb, Wvb);
  // QKV projections
  gemm_bt2<0,0><<<dim3(16, 32), blk, 0, stream>>>(Xb, Wqb, Qws, 2048, 2048, 2048);
  gemm_kv<<<dim3(8, 32), blk, 0, stream>>>(Xb, Wkb, Wvb, Kws, VTws, 2048);
  f32_to_bf16<<<dim3(2048 * 2048 / 8 / 256), blk, 0, stream>>>(wo, Wob, 2048 * 2048);
  rope_kernel<<<dim3((4096 * 2048 / 8 + 4096 * 512 / 8) / 256), blk, 0, stream>>>(Qws, Kws, fc, fs);
  // Flash attention
  attn_kernel<<<dim3(16, 32, 2), blk, 0, stream>>>(Qws, Kws, VTws, Ows);
  // Output projection -> f32
  gemm_bt2<1,0><<<dim3(16, 32), blk, 0, stream>>>(Ows, Wob, out, 2048, 2048, 2048);
}